// Round 1
// baseline (467.156 us; speedup 1.0000x reference)
//
#include <hip/hip_runtime.h>

// NeighborConsistencyLoss: loss = mean_s(1 - mean_k cos(z[c_s], z[knn[c_s,k]]))
//   z:[N,512] f32, knn:[N,32] i32, samp:[S] i32 -> scalar f32.
// R3: one block per sample (S=1000 blocks x 4 waves), 8 neighbors per wave.
//   - center row loaded once per wave (4x/sample vs 8x in R2): -8 MB traffic
//   - all 18 float4 gather loads (2 center + 16 neighbor) issued before any
//     use: 18 KB in flight per wave, ~288 KB/CU >> 9 KB/CU BW-latency product
//   - 17 independent butterflies (cn + 8x{dp,nn}), all statically indexed
// Issued traffic ~72 MB (64 MB unique neighbor rows). BW floor ~11 us.
// NOTE: measured dur_us is dominated by harness workspace-poison fill
// (1.6384 GB @ ~250 us, 81% HBM peak, visible as fillBufferAligned in
// rocprof) + input restore; this kernel's own cost is est. 15-25 us.

#define DDIM 512
#define KNN 32
#define EPSV 1e-8f

__global__ __launch_bounds__(256) void ncl_kernel(
    const float* __restrict__ z,
    const int* __restrict__ knn,
    const int* __restrict__ samp,
    float* __restrict__ block_sums) {
    const int s    = blockIdx.x;          // sample index
    const int lane = threadIdx.x & 63;
    const int wave = threadIdx.x >> 6;    // 4 waves x 8 neighbors = 32

    const int cidx = samp[s];             // block-uniform
    const int* __restrict__ krow = knn + (size_t)cidx * KNN + wave * 8;

    int idx[8];
    #pragma unroll
    for (int j = 0; j < 8; ++j) idx[j] = krow[j];

    // Issue every gather load before any use: 18 x 1KB-per-wave loads in flight.
    const float4* __restrict__ crow = (const float4*)(z + (size_t)cidx * DDIM);
    const float4 c0 = crow[lane];
    const float4 c1 = crow[64 + lane];

    float4 n0[8], n1[8];
    #pragma unroll
    for (int j = 0; j < 8; ++j) {
        const float4* __restrict__ r = (const float4*)(z + (size_t)idx[j] * DDIM);
        n0[j] = r[lane];
        n1[j] = r[64 + lane];
    }

    // Center self-dot (8 elements per lane).
    float cn = c0.x * c0.x;
    cn = fmaf(c0.y, c0.y, cn);
    cn = fmaf(c0.z, c0.z, cn);
    cn = fmaf(c0.w, c0.w, cn);
    cn = fmaf(c1.x, c1.x, cn);
    cn = fmaf(c1.y, c1.y, cn);
    cn = fmaf(c1.z, c1.z, cn);
    cn = fmaf(c1.w, c1.w, cn);

    // Per-neighbor dot + self-dot. All indices compile-time via unroll.
    float dp[8], nn[8];
    #pragma unroll
    for (int j = 0; j < 8; ++j) {
        float d = c0.x * n0[j].x;
        float q = n0[j].x * n0[j].x;
        d = fmaf(c0.y, n0[j].y, d); q = fmaf(n0[j].y, n0[j].y, q);
        d = fmaf(c0.z, n0[j].z, d); q = fmaf(n0[j].z, n0[j].z, q);
        d = fmaf(c0.w, n0[j].w, d); q = fmaf(n0[j].w, n0[j].w, q);
        d = fmaf(c1.x, n1[j].x, d); q = fmaf(n1[j].x, n1[j].x, q);
        d = fmaf(c1.y, n1[j].y, d); q = fmaf(n1[j].y, n1[j].y, q);
        d = fmaf(c1.z, n1[j].z, d); q = fmaf(n1[j].z, n1[j].z, q);
        d = fmaf(c1.w, n1[j].w, d); q = fmaf(n1[j].w, n1[j].w, q);
        dp[j] = d;
        nn[j] = q;
    }

    // 17 independent butterflies; per-step ops are mutually independent.
    #pragma unroll
    for (int off = 32; off; off >>= 1) {
        cn += __shfl_xor(cn, off, 64);
        #pragma unroll
        for (int j = 0; j < 8; ++j) {
            dp[j] += __shfl_xor(dp[j], off, 64);
            nn[j] += __shfl_xor(nn[j], off, 64);
        }
    }

    __shared__ float red[4];
    if (lane == 0) {
        const float cnorm = sqrtf(cn);
        float w = 0.0f;
        #pragma unroll
        for (int j = 0; j < 8; ++j)
            w += dp[j] / fmaxf(cnorm * sqrtf(nn[j]), EPSV);
        red[wave] = w;
    }
    __syncthreads();
    if (threadIdx.x == 0)
        block_sums[s] = red[0] + red[1] + red[2] + red[3];
}

__global__ __launch_bounds__(256) void ncl_finalize_kernel(
    const float* __restrict__ block_sums, float* __restrict__ out, int nblocks, float inv_sk) {
    __shared__ float red[256];
    float acc = 0.0f;
    for (int i = threadIdx.x; i < nblocks; i += 256) acc += block_sums[i];
    red[threadIdx.x] = acc;
    __syncthreads();
    #pragma unroll
    for (int off = 128; off; off >>= 1) {
        if (threadIdx.x < off) red[threadIdx.x] += red[threadIdx.x + off];
        __syncthreads();
    }
    if (threadIdx.x == 0)
        out[0] = 1.0f - red[0] * inv_sk;
}

extern "C" void kernel_launch(void* const* d_in, const int* in_sizes, int n_in,
                              void* d_out, int out_size, void* d_ws, size_t ws_size,
                              hipStream_t stream) {
    const float* z    = (const float*)d_in[0];
    const int*   knn  = (const int*)d_in[1];
    const int*   samp = (const int*)d_in[2];
    const int    S    = in_sizes[2];

    float* block_sums = (float*)d_ws;  // S floats of scratch
    float* out        = (float*)d_out;

    ncl_kernel<<<S, 256, 0, stream>>>(z, knn, samp, block_sums);
    ncl_finalize_kernel<<<1, 256, 0, stream>>>(block_sums, out, S,
                                               1.0f / ((float)S * (float)KNN));
}